// Round 2
// baseline (98.791 us; speedup 1.0000x reference)
//
#include <hip/hip_runtime.h>

#define HH 2048
#define WW 2048
#define NF 64
#define MAXD 12
#define ROWS_PER_BLOCK 2
#define STRIP 16
#define PXB (ROWS_PER_BLOCK * WW)   // 4096 pixels per block

// Single fused kernel:
//  Phase 0: per-block argmax of frame_selection rows (first-max, strict >),
//           tables staged into LDS as int2 {ratio_bits, childL|childR<<16}.
//  Phase 1: run-cached descent. Each thread owns a 16-px x-strip; one descent
//           yields the leaf rect, so run_end = x0+w fills multiple pixels.
//           Batched in a wave-uniform while(__any) loop so wave cost is
//           max-runs-per-lane, not sum-over-pixels.
//  Phase 2: coalesced float4 writes per plane, idx from LDS u8 staging.
__global__ __launch_bounds__(256)
void fractal_kernel(const float* __restrict__ colors,   // [NF,3]
                    const float* __restrict__ sel,      // [NF,2,NF]
                    const float* __restrict__ ratios,   // [NF]
                    float* __restrict__ out) {          // [3,HH,WW]
    __shared__ int2  s_node[NF];         // .x = ratio bits, .y = childL | childR<<16
    __shared__ float s_colp[3 * NF];     // plane-major colors
    __shared__ int   s_amax[2 * NF];
    __shared__ unsigned char s_idx[PXB];

    int t = threadIdx.x;

    // ---- Phase 0: argmax + table staging ----
    if (t < 2 * NF) {
        const float4* row = (const float4*)(sel + t * NF);
        float4 v0 = row[0];
        float best = v0.x;
        int bi = 0;
        #pragma unroll
        for (int j = 0; j < NF / 4; ++j) {
            float4 v = row[j];
            if (v.x > best) { best = v.x; bi = 4 * j + 0; }
            if (v.y > best) { best = v.y; bi = 4 * j + 1; }
            if (v.z > best) { best = v.z; bi = 4 * j + 2; }
            if (v.w > best) { best = v.w; bi = 4 * j + 3; }
        }
        s_amax[t] = bi;
    }
    if (t < NF) {
        s_node[t].x = __float_as_int(ratios[t]);
    }
    if (t < 3 * NF) {
        int f = t / 3, c = t - 3 * f;          // t = f*3 + c
        s_colp[c * NF + f] = colors[t];        // plane-major
    }
    __syncthreads();
    if (t < NF) {
        s_node[t].y = s_amax[2 * t] | (s_amax[2 * t + 1] << 16);
    }
    __syncthreads();

    // ---- Phase 1: run-cached descent ----
    int r  = t >> 7;                 // row within block: 0..1
    int c  = t & 127;                // strip column: 0..127
    int y  = blockIdx.x * ROWS_PER_BLOCK + r;
    int xb = c * STRIP;
    int xend = xb + STRIP;
    int x = xb;
    unsigned long long lo = 0, hi = 0;   // 16 packed u8 leaf indices

    while (__any(x < xend)) {
        if (x < xend) {
            int i = 0, x0 = 0, y0 = 0, w = WW, h = HH;
            #pragma unroll 1
            for (int d = 0; d < MAXD; ++d) {
                if (w < 2 || h < 2) break;
                int2 nd = s_node[i];
                float ratio = __int_as_float(nd.x);
                int chl = nd.y & 0xffff;
                int chr = nd.y >> 16;
                if (i & 1) {                       // vertical split
                    int lw = (int)floorf((float)w * ratio);
                    lw = lw < 1 ? 1 : lw;
                    if (x - x0 < lw) { i = chl; w = lw; }
                    else             { i = chr; x0 += lw; w -= lw; }
                } else {                           // horizontal split
                    int th = (int)floorf((float)h * ratio);
                    th = th < 1 ? 1 : th;
                    if (y - y0 < th) { i = chl; h = th; }
                    else             { i = chr; y0 += th; h -= th; }
                }
            }
            int re = x0 + w;                       // leaf rect covers [x0, x0+w)
            if (re > xend) re = xend;
            for (; x < re; ++x) {
                int o = x - xb;
                unsigned long long v =
                    (unsigned long long)(unsigned)i << ((o & 7) * 8);
                if (o < 8) lo |= v; else hi |= v;
            }
        }
    }

    {
        ulonglong2 u;
        u.x = lo; u.y = hi;
        *(ulonglong2*)(s_idx + (r * WW + xb)) = u;   // ds_write_b128, 16B aligned
    }
    __syncthreads();

    // ---- Phase 2: coalesced output ----
    const int plane = HH * WW;
    int base = blockIdx.x * PXB;
    #pragma unroll
    for (int pl = 0; pl < 3; ++pl) {
        const float* cp = s_colp + pl * NF;
        #pragma unroll
        for (int j = 0; j < PXB / (256 * 4); ++j) {   // 4 float4s per plane
            int p4 = (j * 256 + t) * 4;
            unsigned q = *(const unsigned*)(s_idx + p4);
            float4 v;
            v.x = cp[q & 0xff];
            v.y = cp[(q >> 8) & 0xff];
            v.z = cp[(q >> 16) & 0xff];
            v.w = cp[q >> 24];
            *(float4*)(out + pl * plane + base + p4) = v;
        }
    }
}

extern "C" void kernel_launch(void* const* d_in, const int* in_sizes, int n_in,
                              void* d_out, int out_size, void* d_ws, size_t ws_size,
                              hipStream_t stream) {
    const float* frame_colors    = (const float*)d_in[0];  // [64,3]
    const float* frame_selection = (const float*)d_in[1];  // [64,2,64]
    const float* split_ratios    = (const float*)d_in[2];  // [64]
    float* out = (float*)d_out;

    fractal_kernel<<<HH / ROWS_PER_BLOCK, 256, 0, stream>>>(
        frame_colors, frame_selection, split_ratios, out);
}